// Round 9
// baseline (1880.681 us; speedup 1.0000x reference)
//
#include <hip/hip_runtime.h>

#define IN_F 128
#define HID_F 64
#define BKT_SHIFT 9            // 512 nodes per bucket
#define BKT_SIZE 512
#define CHUNK 4096             // edges per chunk in binning phases
#define NBLK 1024              // persistent grid: 4 blocks/CU guaranteed resident
#define MAGIC 0x13572468

typedef unsigned short ushort_t;
typedef __attribute__((ext_vector_type(8))) short bf16x8;
typedef __attribute__((ext_vector_type(8))) unsigned short u16x8;
typedef __attribute__((ext_vector_type(4))) float f32x4;

__device__ inline ushort_t f2bf(float f) {     // RNE fp32 -> bf16 bits
    unsigned u = __float_as_uint(f);
    u += 0x7FFFu + ((u >> 16) & 1u);
    return (ushort_t)(u >> 16);
}
__device__ inline float bf2f(ushort_t u) {
    return __uint_as_float((unsigned)u << 16);
}

// software grid barrier (device-scope; one dedicated counter per barrier)
__device__ inline void gbar(int* ctr, int idx) {
    __syncthreads();
    if (threadIdx.x == 0) {
        __threadfence();
        __hip_atomic_fetch_add(ctr + idx, 1, __ATOMIC_ACQ_REL, __HIP_MEMORY_SCOPE_AGENT);
        while (__hip_atomic_load(ctr + idx, __ATOMIC_ACQUIRE, __HIP_MEMORY_SCOPE_AGENT) < (int)gridDim.x)
            __builtin_amdgcn_s_sleep(1);
        __threadfence();
    }
    __syncthreads();
}

__global__ __launch_bounds__(256, 4) void k_fused(
        const float* __restrict__ x, const int* __restrict__ ei,
        const float* __restrict__ W1, const float* __restrict__ b1,
        const float* __restrict__ W2, const float* __restrict__ b2,
        float* __restrict__ out, char* __restrict__ ws, int N, int E) {
    const int tid = threadIdx.x;
    const int bid = blockIdx.x;
    const int nbE = (E + CHUNK - 1) / CHUNK;       // 391
    const int nbB = (N + BKT_SIZE - 1) / BKT_SIZE; // 196

    const int* src = ei;
    const int* dst = ei + E;

    const size_t MB = 1u << 20;
    int*      ctr    = (int*)     (ws);                // 32 ints: 0..15 barriers, 16 flag
    int*      gcount = (int*)     (ws + 12288);        // 256 ints
    ushort_t* Bp1    = (ushort_t*)(ws + 16384);        // 8192 bf16
    ushort_t* Bp2    = (ushort_t*)(ws + 49152);        // 4096 bf16
    int*      rowptr = (int*)     (ws + 1 * MB);       // N+1 ints
    float*    dinv   = (float*)   (ws + 2 * MB);       // N floats (+slack)
    unsigned* gbin   = (unsigned*)(ws + 3 * MB);       // E uints
    int*      ghist  = (int*)     (ws + 10 * MB);      // nbE*256 ints
    int*      col    = (int*)     (ws + 11 * MB);      // E ints
    ushort_t* xws    = (ushort_t*)(ws + 20 * MB);      // N*64 bf16
    ushort_t* h      = (ushort_t*)(ws + 36 * MB);      // N*64 bf16

    __shared__ int sh_a[256];
    __shared__ int sh_b[256];
    __shared__ int sh_cnt[BKT_SIZE];
    __shared__ int sh_pos[BKT_SIZE];

    // ---- init handshake: ws is re-poisoned 0xAA before every launch ----
    if (bid == 0) {
        if (tid < 16) ctr[tid] = 0;
        __syncthreads();
        if (tid == 0) {
            __threadfence();
            __hip_atomic_store(ctr + 16, MAGIC, __ATOMIC_RELEASE, __HIP_MEMORY_SCOPE_AGENT);
        }
    } else if (tid == 0) {
        while (__hip_atomic_load(ctr + 16, __ATOMIC_ACQUIRE, __HIP_MEMORY_SCOPE_AGENT) != MAGIC)
            __builtin_amdgcn_s_sleep(1);
        __threadfence();
    }
    __syncthreads();

    // ---- phase 1: pack W into MFMA B-frag order + per-chunk histogram ----
    for (int tg = bid * 256 + tid; tg < 12288; tg += NBLK * 256) {
        int id = (tg < 8192) ? tg : tg - 8192;
        int j = id & 7, lane = (id >> 3) & 63, t = (id >> 9) & 3, s = id >> 11;
        int k = s * 32 + ((lane >> 4) << 3) + j;
        int n = t * 16 + (lane & 15);
        if (tg < 8192) Bp1[id] = f2bf(W1[k * 64 + n]);
        else           Bp2[id] = f2bf(W2[k * 64 + n]);
    }
    for (int c = bid; c < nbE; c += NBLK) {
        sh_a[tid] = 0;
        __syncthreads();
        int e0 = c * CHUNK, e1 = min(e0 + CHUNK, E);
        for (int e = e0 + tid; e < e1; e += 256)
            atomicAdd(&sh_a[dst[e] >> BKT_SHIFT], 1);
        __syncthreads();
        ghist[c * 256 + tid] = sh_a[tid];
        __syncthreads();
    }
    gbar(ctr, 0);

    // ---- phase 2: per-bucket exclusive scan over chunk counts ----
    for (int b = bid; b < 256; b += NBLK) {
        int j0 = 2 * tid, j1 = 2 * tid + 1;
        int v0 = (j0 < nbE) ? ghist[j0 * 256 + b] : 0;
        int v1 = (j1 < nbE) ? ghist[j1 * 256 + b] : 0;
        int p = v0 + v1;
        sh_a[tid] = p;
        __syncthreads();
        for (int off = 1; off < 256; off <<= 1) {
            int v = (tid >= off) ? sh_a[tid - off] : 0;
            __syncthreads();
            sh_a[tid] += v;
            __syncthreads();
        }
        int excl = sh_a[tid] - p;
        if (j0 < nbE) ghist[j0 * 256 + b] = excl;
        if (j1 < nbE) ghist[j1 * 256 + b] = excl + v0;
        if (tid == 255) gcount[b] = sh_a[255];
        __syncthreads();
    }
    gbar(ctr, 1);

    // ---- bucket bases (every block computes; kept in a register) ----
    int baseReg;
    {
        int c = gcount[tid];
        sh_a[tid] = c;
        __syncthreads();
        for (int off = 1; off < 256; off <<= 1) {
            int v = (tid >= off) ? sh_a[tid - off] : 0;
            __syncthreads();
            sh_a[tid] += v;
            __syncthreads();
        }
        baseReg = sh_a[tid] - c;   // exclusive bucket base
    }
    __syncthreads();

    // ---- phase 3: scatter edges into bucket-contiguous gbin ----
    sh_cnt[tid] = baseReg;          // persist bases across chunk loop
    __syncthreads();
    for (int c = bid; c < nbE; c += NBLK) {
        sh_b[tid] = ghist[c * 256 + tid] + sh_cnt[tid];
        __syncthreads();
        int e0 = c * CHUNK, e1 = min(e0 + CHUNK, E);
        for (int e = e0 + tid; e < e1; e += 256) {
            int d = dst[e];
            int bk = d >> BKT_SHIFT;
            int p = atomicAdd(&sh_b[bk], 1);
            gbin[p] = ((unsigned)(d & (BKT_SIZE - 1)) << 23) | (unsigned)src[e];
        }
        __syncthreads();
    }
    gbar(ctr, 2);

    // ---- phase 4: per-bucket CSR fill (rowptr, dinv, col) ----
    if (bid == 0 && tid == 0) rowptr[N] = E;
    for (int b = bid; b < nbB; b += NBLK) {
        sh_a[tid] = baseReg;
        __syncthreads();
        int e0 = sh_a[b];
        int e1 = (b < 255) ? sh_a[b + 1] : E;
        __syncthreads();
        sh_cnt[tid] = 0; sh_cnt[tid + 256] = 0;
        __syncthreads();
        for (int e = e0 + tid; e < e1; e += 256)
            atomicAdd(&sh_cnt[gbin[e] >> 23], 1);
        __syncthreads();
        int c0 = sh_cnt[2 * tid], c1 = sh_cnt[2 * tid + 1];
        int p2 = c0 + c1;
        sh_a[tid] = p2;
        __syncthreads();
        for (int off = 1; off < 256; off <<= 1) {
            int v = (tid >= off) ? sh_a[tid - off] : 0;
            __syncthreads();
            sh_a[tid] += v;
            __syncthreads();
        }
        int excl = sh_a[tid] - p2;
        sh_pos[2 * tid] = excl;
        sh_pos[2 * tid + 1] = excl + c0;
        __syncthreads();
        int n0 = b << BKT_SHIFT;
        #pragma unroll
        for (int i = tid; i < BKT_SIZE; i += 256) {
            int n = n0 + i;
            if (n < N) {
                rowptr[n] = e0 + sh_pos[i];
                dinv[n] = rsqrtf((float)sh_cnt[i] + 1.0f);   // +1 self-loop
            }
        }
        __syncthreads();
        for (int e = e0 + tid; e < e1; e += 256) {
            unsigned v = gbin[e];
            int p = atomicAdd(&sh_pos[v >> 23], 1);
            col[e0 + p] = (int)(v & 0x7FFFFFu);
        }
        __syncthreads();
    }
    gbar(ctr, 3);

    // ---- GEMM tile helper (templated over K / A-type), grid-stride ----
    const int nTiles = (N + 63) / 64;
    {   // layer-1 GEMM: xws = bf16((x @ W1) * dinv)
        int wave = tid >> 6, lane = tid & 63;
        int m = lane & 15, q = lane >> 4;
        for (int t0 = bid; t0 < nTiles; t0 += NBLK) {
            int row0 = t0 * 64 + wave * 16;
            int arow = row0 + m;
            int arowc = (arow < N) ? arow : (N - 1);
            f32x4 acc[4] = {};
            #pragma unroll
            for (int s = 0; s < IN_F / 32; ++s) {
                const float* ap = x + (size_t)arowc * IN_F + s * 32 + q * 8;
                float4 x0 = *(const float4*)ap;
                float4 x1 = *(const float4*)(ap + 4);
                bf16x8 af;
                af[0] = (short)f2bf(x0.x); af[1] = (short)f2bf(x0.y);
                af[2] = (short)f2bf(x0.z); af[3] = (short)f2bf(x0.w);
                af[4] = (short)f2bf(x1.x); af[5] = (short)f2bf(x1.y);
                af[6] = (short)f2bf(x1.z); af[7] = (short)f2bf(x1.w);
                #pragma unroll
                for (int t = 0; t < 4; ++t) {
                    bf16x8 bf = *(const bf16x8*)(Bp1 + (size_t)((s * 4 + t) * 64 + lane) * 8);
                    acc[t] = __builtin_amdgcn_mfma_f32_16x16x32_bf16(af, bf, acc[t], 0, 0, 0);
                }
            }
            int orow0 = row0 + q * 4;
            float4 d4 = *(const float4*)(dinv + orow0);
            #pragma unroll
            for (int r = 0; r < 4; ++r) {
                int row = orow0 + r;
                if (row < N) {
                    float dn = (r == 0) ? d4.x : (r == 1) ? d4.y : (r == 2) ? d4.z : d4.w;
                    #pragma unroll
                    for (int t = 0; t < 4; ++t)
                        xws[(size_t)row * 64 + t * 16 + m] = f2bf(acc[t][r] * dn);
                }
            }
        }
    }
    gbar(ctr, 4);

    // ---- aggregate phase (8 lanes/node, batches of 8 gathers) ----
    #define AGG_PHASE(OUTF, OUTB, RELU_BF16)                                     \
    {                                                                            \
        int i = tid & 7;                                                         \
        const ushort_t* base = xws + i * 8;                                      \
        for (int n = bid * 32 + (tid >> 3); n < N; n += NBLK * 32) {             \
            int beg = rowptr[n], end = rowptr[n + 1];                            \
            float dn = dinv[n];                                                  \
            u16x8 sv = *(const u16x8*)(base + (size_t)n * 64);                   \
            float a[8];                                                          \
            _Pragma("unroll") for (int k = 0; k < 8; ++k) a[k] = bf2f(sv[k]);    \
            int e = beg;                                                         \
            for (; e + 8 <= end; e += 8) {                                       \
                int c[8];                                                        \
                _Pragma("unroll") for (int j = 0; j < 8; ++j) c[j] = col[e + j]; \
                u16x8 v[8];                                                      \
                _Pragma("unroll") for (int j = 0; j < 8; ++j)                    \
                    v[j] = *(const u16x8*)(base + (size_t)c[j] * 64);            \
                _Pragma("unroll") for (int j = 0; j < 8; ++j)                    \
                    _Pragma("unroll") for (int k = 0; k < 8; ++k)                \
                        a[k] += bf2f(v[j][k]);                                   \
            }                                                                    \
            if (e + 4 <= end) {                                                  \
                int c[4];                                                        \
                _Pragma("unroll") for (int j = 0; j < 4; ++j) c[j] = col[e + j]; \
                u16x8 v[4];                                                      \
                _Pragma("unroll") for (int j = 0; j < 4; ++j)                    \
                    v[j] = *(const u16x8*)(base + (size_t)c[j] * 64);            \
                _Pragma("unroll") for (int j = 0; j < 4; ++j)                    \
                    _Pragma("unroll") for (int k = 0; k < 8; ++k)                \
                        a[k] += bf2f(v[j][k]);                                   \
                e += 4;                                                          \
            }                                                                    \
            for (; e < end; ++e) {                                               \
                u16x8 v = *(const u16x8*)(base + (size_t)col[e] * 64);           \
                _Pragma("unroll") for (int k = 0; k < 8; ++k) a[k] += bf2f(v[k]);\
            }                                                                    \
            const float* bia = RELU_BF16 ? b1 : b2;                              \
            float4 bb0 = *(const float4*)(bia + i * 8);                          \
            float4 bb1 = *(const float4*)(bia + i * 8 + 4);                      \
            float r[8];                                                          \
            r[0] = dn * a[0] + bb0.x; r[1] = dn * a[1] + bb0.y;                  \
            r[2] = dn * a[2] + bb0.z; r[3] = dn * a[3] + bb0.w;                  \
            r[4] = dn * a[4] + bb1.x; r[5] = dn * a[5] + bb1.y;                  \
            r[6] = dn * a[6] + bb1.z; r[7] = dn * a[7] + bb1.w;                  \
            if (RELU_BF16) {                                                     \
                u16x8 o;                                                         \
                _Pragma("unroll") for (int k = 0; k < 8; ++k)                    \
                    o[k] = f2bf(fmaxf(r[k], 0.f));                               \
                *(u16x8*)(OUTB + (size_t)n * 64 + i * 8) = o;                    \
            } else {                                                             \
                float4 o0 = {r[0], r[1], r[2], r[3]};                            \
                float4 o1 = {r[4], r[5], r[6], r[7]};                            \
                *(float4*)(OUTF + (size_t)n * 64 + i * 8) = o0;                  \
                *(float4*)(OUTF + (size_t)n * 64 + i * 8 + 4) = o1;              \
            }                                                                    \
        }                                                                        \
    }

    AGG_PHASE(out, h, 1)          // layer-1: h = bf16(relu(...))
    gbar(ctr, 5);

    {   // layer-2 GEMM: xws = bf16((h @ W2) * dinv)
        int wave = tid >> 6, lane = tid & 63;
        int m = lane & 15, q = lane >> 4;
        for (int t0 = bid; t0 < nTiles; t0 += NBLK) {
            int row0 = t0 * 64 + wave * 16;
            int arow = row0 + m;
            int arowc = (arow < N) ? arow : (N - 1);
            f32x4 acc[4] = {};
            #pragma unroll
            for (int s = 0; s < HID_F / 32; ++s) {
                bf16x8 af = *(const bf16x8*)(h + (size_t)arowc * HID_F + s * 32 + q * 8);
                #pragma unroll
                for (int t = 0; t < 4; ++t) {
                    bf16x8 bf = *(const bf16x8*)(Bp2 + (size_t)((s * 4 + t) * 64 + lane) * 8);
                    acc[t] = __builtin_amdgcn_mfma_f32_16x16x32_bf16(af, bf, acc[t], 0, 0, 0);
                }
            }
            int orow0 = row0 + q * 4;
            float4 d4 = *(const float4*)(dinv + orow0);
            #pragma unroll
            for (int r = 0; r < 4; ++r) {
                int row = orow0 + r;
                if (row < N) {
                    float dn = (r == 0) ? d4.x : (r == 1) ? d4.y : (r == 2) ? d4.z : d4.w;
                    #pragma unroll
                    for (int t = 0; t < 4; ++t)
                        xws[(size_t)row * 64 + t * 16 + m] = f2bf(acc[t][r] * dn);
                }
            }
        }
    }
    gbar(ctr, 6);

    AGG_PHASE(out, h, 0)          // layer-2: out = fp32
}

// ---------------- launch ----------------

extern "C" void kernel_launch(void* const* d_in, const int* in_sizes, int n_in,
                              void* d_out, int out_size, void* d_ws, size_t ws_size,
                              hipStream_t stream) {
    const float* x  = (const float*)d_in[0];
    const int*   ei = (const int*)d_in[1];
    const float* W1 = (const float*)d_in[2];
    const float* b1 = (const float*)d_in[3];
    const float* W2 = (const float*)d_in[4];
    const float* b2 = (const float*)d_in[5];
    float* out = (float*)d_out;

    const int N = in_sizes[0] / IN_F;
    const int E = in_sizes[1] / 2;

    k_fused<<<NBLK, 256, 0, stream>>>(x, ei, W1, b1, W2, b2, out, (char*)d_ws, N, E);
}